// Round 4
// baseline (200.944 us; speedup 1.0000x reference)
//
#include <hip/hip_runtime.h>
#include <hip/hip_bf16.h>

// PAM module R10: q/k/v 1x1 projections -> bf16 MFMA attention -> gamma*out + x.
// R9 post-mortem: attn floor (~97us) explained quantitatively: each 32-row
// block streams the full per-batch K+V (4MB) from L2 -> 2GB total / 97us =
// 20.6 TB/s = ~60% of the per-XCD L2 ceiling (4.3 TB/s x 8). BW-bound, which
// is why scheduling (R7) and latency (R8) grafts were null. R10: halve the
// traffic. n-strip 64 per block, 512 threads = 8 waves (4 m-quarters x 2
// n-groups); K/V tile staged ONCE per block into double-buffered LDS via
// cooperative global_load_lds (linear chunk layout = workspace layout), all
// 8 waves read fragments from LDS. One vmcnt(0)+barrier per tile (2-phase
// template). Per-wave compute is byte-identical to the verified R6/R7 wave
// code. L2 reads: 2GB -> 1GB. LDS 132KB -> 1 block/CU (2 waves/SIMD, same
// as before). K reg ping-pong + dual-sacc dropped (proven null).
//
// Workspace layouts (bf16, chunk = 64 lanes x 16B = 1KB, frag-major):
//   qf_ws[b][strip32][ni2][kc4][lane]         8MB  (PRE-SCALED by log2e)
//   kt   [b][tile128][chunk32 = mb*4+kc][lane]{8}   8MB
//   vt   [b][tile128][chunk32 = cb*4+wq][lane]{8}   8MB

typedef __bf16 v8bf __attribute__((ext_vector_type(8)));
typedef float  v4f  __attribute__((ext_vector_type(4)));

#define B_ 8
#define C_ 128
#define N_ 4096

// Swizzled LDS offset (in shorts) for proj's 128x160 tiles (R9, kept).
#define SWZ(R, COLS) ((R) * 160 + (((((COLS) >> 3) ^ (((R) >> 2) & 15))) << 3) + ((COLS) & 7))

static __device__ __forceinline__ unsigned short f2bf_rne(float f) {
    union { float f; unsigned u; } v; v.f = f;
    return (unsigned short)((v.u + 0x7fffu + ((v.u >> 16) & 1u)) >> 16);
}
static __device__ __forceinline__ unsigned fbits(float f) {
    union { float f; unsigned u; } v; v.f = f; return v.u;
}

// ---------------------------------------------------------------------------
// Kernel 1: q/k/v projections (R9 verbatim: swizzled 160-stride LDS tiles).
// ---------------------------------------------------------------------------
__global__ __launch_bounds__(256, 2) void proj_kernel(
    const float* __restrict__ x,
    const float* __restrict__ dw_q, const float* __restrict__ pw_q,
    const float* __restrict__ dw_k, const float* __restrict__ pw_k,
    const float* __restrict__ dw_v, const float* __restrict__ pw_v,
    unsigned short* __restrict__ qf_ws, unsigned short* __restrict__ kt,
    unsigned short* __restrict__ vt)
{
    __shared__ unsigned short xT[128 * 160];  // xT[n][c], swizzled
    __shared__ unsigned short Ws[128 * 160];  // W[o][c], swizzled; reused as store scratch

    const int bid = blockIdx.x;
    const int bb  = bid & 7;
    const int t   = (bid >> 3) & 31;
    const int pp  = bid >> 8;            // 0:q 1:k 2:v
    const int n0  = t * 128;
    const int tid = threadIdx.x;
    const int w    = tid >> 6;
    const int lane = tid & 63;
    const int quad = lane >> 4;
    const int l16  = lane & 15;

    #pragma unroll
    for (int k = 0; k < 16; ++k) {
        const int idx = tid + k * 256;
        const int c  = idx >> 5;
        const int nq = idx & 31;
        float4 f = *(const float4*)(x + ((size_t)(bb * C_ + c)) * N_ + n0 + nq * 4);
        xT[SWZ(nq * 4 + 0, c)] = f2bf_rne(f.x);
        xT[SWZ(nq * 4 + 1, c)] = f2bf_rne(f.y);
        xT[SWZ(nq * 4 + 2, c)] = f2bf_rne(f.z);
        xT[SWZ(nq * 4 + 3, c)] = f2bf_rne(f.w);
    }
    const float* pw = (pp == 0) ? pw_q : (pp == 1) ? pw_k : pw_v;
    const float* dw = (pp == 0) ? dw_q : (pp == 1) ? dw_k : dw_v;
    const float qs = (pp == 0) ? 1.4426950408889634f : 1.0f;
    #pragma unroll
    for (int k = 0; k < 16; ++k) {
        const int idx = tid + k * 256;
        const int o  = idx >> 5;
        const int c4 = (idx & 31) * 4;
        float4 p4 = *(const float4*)(pw + o * 128 + c4);
        float4 d4 = *(const float4*)(dw + c4);
        unsigned lo = (unsigned)f2bf_rne(p4.x * d4.x * qs) | ((unsigned)f2bf_rne(p4.y * d4.y * qs) << 16);
        unsigned hi = (unsigned)f2bf_rne(p4.z * d4.z * qs) | ((unsigned)f2bf_rne(p4.w * d4.w * qs) << 16);
        *(unsigned long long*)&Ws[SWZ(o, c4)] =
            (unsigned long long)lo | ((unsigned long long)hi << 32);
    }
    __syncthreads();

    const unsigned short* As = (pp < 2) ? xT : Ws;
    const unsigned short* Bs = (pp < 2) ? Ws : xT;

    v4f acc[2][8];
    #pragma unroll
    for (int i = 0; i < 2; ++i)
        #pragma unroll
        for (int j = 0; j < 8; ++j)
            acc[i][j] = (v4f){0.f, 0.f, 0.f, 0.f};

    #pragma unroll
    for (int kc = 0; kc < 4; ++kc) {
        v8bf av[2];
        #pragma unroll
        for (int i = 0; i < 2; ++i)
            av[i] = *(const v8bf*)&As[SWZ(w * 32 + i * 16 + l16, kc * 32 + quad * 8)];
        #pragma unroll
        for (int cb = 0; cb < 8; ++cb) {
            v8bf bv = *(const v8bf*)&Bs[SWZ(cb * 16 + l16, kc * 32 + quad * 8)];
            acc[0][cb] = __builtin_amdgcn_mfma_f32_16x16x32_bf16(av[0], bv, acc[0][cb], 0, 0, 0);
            acc[1][cb] = __builtin_amdgcn_mfma_f32_16x16x32_bf16(av[1], bv, acc[1][cb], 0, 0, 0);
        }
    }
    __syncthreads();

    unsigned short* sc = Ws;
    #pragma unroll
    for (int mi = 0; mi < 2; ++mi)
        #pragma unroll
        for (int cb = 0; cb < 8; ++cb)
            #pragma unroll
            for (int r = 0; r < 4; ++r)
                sc[SWZ(w * 32 + mi * 16 + quad * 4 + r, cb * 16 + l16)] =
                    f2bf_rne(acc[mi][cb][r]);
    __syncthreads();

    if (pp == 0) {
        unsigned short* dst = qf_ws + ((size_t)(bb * 64 + t * 2)) * 8192;
        #pragma unroll
        for (int p = 0; p < 8; ++p) {
            const int g     = p * 4 + w;
            const int strip = g >> 4, ni = (g >> 2) & 3, kc = g & 3;
            *(uint4*)(dst + ((size_t)g * 64 + lane) * 8) =
                *(const uint4*)&sc[SWZ(strip * 64 + ni * 16 + l16, kc * 32 + quad * 8)];
        }
    } else if (pp == 1) {
        unsigned short* dst = kt + ((size_t)(bb * 32 + t)) * 16384;
        #pragma unroll
        for (int p = 0; p < 8; ++p) {
            const int g  = p * 4 + w;
            const int mb = g >> 2, kc = g & 3;
            *(uint4*)(dst + ((size_t)g * 64 + lane) * 8) =
                *(const uint4*)&sc[SWZ(mb * 16 + l16, kc * 32 + quad * 8)];
        }
    } else {
        unsigned short* dst = vt + ((size_t)(bb * 32 + t)) * 16384;
        #pragma unroll
        for (int p = 0; p < 8; ++p) {
            const int d  = p * 256 + tid;
            const int cb = d >> 8, wq = (d >> 4) & 15, l = d & 15;
            *(uint4*)(dst + (size_t)d * 8) =
                *(const uint4*)&sc[SWZ(cb * 16 + l, wq * 8)];
        }
    }
}

// ---------------------------------------------------------------------------
// Kernel 2: attention. grid 512 = (b = bid&7, 64-row n-strip = bid>>3).
// 512 thr / 8 waves: wq = w&3 = m-quarter, g = w>>2 = n-group (32 rows each).
// K/V tile staged once per block into LDS (double-buffered); per-wave compute
// identical to the verified R6 wave code.
// ---------------------------------------------------------------------------
#define MFMA(A, B, C) __builtin_amdgcn_mfma_f32_16x16x32_bf16(A, B, C, 0, 0, 0)
#define EXP2(X) __builtin_amdgcn_exp2f(X)
#define PKPERM(EH, EL) __builtin_amdgcn_perm(fbits(EH), fbits(EL), 0x07060302)

// Cooperative stage of one 64KB K+V tile: 64 chunks (1KB = 64 lanes x 16B),
// 8 per wave. Waves 0-3 stage K chunks 0..31, waves 4-7 stage V -> LDS chunks
// 32..63. LDS dest chunk = w*8+j (linear); global src chunk = (w&3)*8+j of
// the kt/vt tile (identity map). Source addr per-lane (+lane*16B), LDS dest
// wave-uniform base (+lane*16B implicit).
#define STAGE(TILE, BUF) { \
    const unsigned short* sp_ = stbase + (size_t)(TILE) * 16384; \
    _Pragma("unroll") \
    for (int j_ = 0; j_ < 8; ++j_) \
        __builtin_amdgcn_global_load_lds( \
            (const __attribute__((address_space(1))) void*)(sp_ + j_ * 512), \
            (__attribute__((address_space(3))) void*)&sm.t[BUF][w * 8 + j_][0][0], \
            16, 0, 0); \
}

// K fragments for this wave's m-quarter: LDS chunks wq*8 + mi*4 + kc.
#define LOADK(BUF) { \
    _Pragma("unroll") \
    for (int mi_ = 0; mi_ < 2; ++mi_) \
        _Pragma("unroll") \
        for (int kc_ = 0; kc_ < 4; ++kc_) \
            kf[mi_][kc_] = *(const v8bf*)&sm.t[BUF][wq * 8 + mi_ * 4 + kc_][lane][0]; \
}

// V fragments: LDS chunks 32 + cb*4 + wq.
#define LOADV(BUF) { \
    _Pragma("unroll") \
    for (int cb_ = 0; cb_ < 8; ++cb_) \
        vv[cb_] = *(const v8bf*)&sm.t[BUF][32 + cb_ * 4 + wq][lane][0]; \
}

#define SCOMP(SC) { \
    _Pragma("unroll") \
    for (int mi_ = 0; mi_ < 2; ++mi_) \
        _Pragma("unroll") \
        for (int ni_ = 0; ni_ < 2; ++ni_) { \
            v4f a_ = MFMA(kf[mi_][0], qf[ni_][0], Z4v); \
            _Pragma("unroll") \
            for (int kc_ = 1; kc_ < 4; ++kc_) \
                a_ = MFMA(kf[mi_][kc_], qf[ni_][kc_], a_); \
            SC[mi_][ni_] = a_; \
        } \
}

#define SOFTMAX(SC) { \
    unsigned pk_[2][2][2]; \
    _Pragma("unroll") \
    for (int mi_ = 0; mi_ < 2; ++mi_) \
        _Pragma("unroll") \
        for (int ni_ = 0; ni_ < 2; ++ni_) { \
            float e0 = EXP2(SC[mi_][ni_][0]), e1 = EXP2(SC[mi_][ni_][1]); \
            float e2 = EXP2(SC[mi_][ni_][2]), e3 = EXP2(SC[mi_][ni_][3]); \
            lpart[ni_] += (e0 + e1) + (e2 + e3); \
            pk_[mi_][ni_][0] = PKPERM(e1, e0); \
            pk_[mi_][ni_][1] = PKPERM(e3, e2); \
        } \
    _Pragma("unroll") \
    for (int ni_ = 0; ni_ < 2; ++ni_) { \
        unsigned sLo = (quad < 2) ? pk_[0][ni_][0] : pk_[1][ni_][0]; \
        unsigned sHi = (quad < 2) ? pk_[0][ni_][1] : pk_[1][ni_][1]; \
        union { unsigned u[4]; v8bf v; } pu; \
        pu.u[0] = (unsigned)__builtin_amdgcn_ds_bpermute(la, (int)sLo); \
        pu.u[1] = (unsigned)__builtin_amdgcn_ds_bpermute(la, (int)sHi); \
        pu.u[2] = (unsigned)__builtin_amdgcn_ds_bpermute(lb, (int)sLo); \
        pu.u[3] = (unsigned)__builtin_amdgcn_ds_bpermute(lb, (int)sHi); \
        pf[ni_] = pu.v; \
    } \
}

#define PVOP { \
    _Pragma("unroll") \
    for (int ni_ = 0; ni_ < 2; ++ni_) \
        _Pragma("unroll") \
        for (int cb_ = 0; cb_ < 8; ++cb_) \
            oacc[cb_][ni_] = MFMA(vv[cb_], pf[ni_], oacc[cb_][ni_]); \
}

__global__ __launch_bounds__(512, 2) void attn_kernel(
    const unsigned short* __restrict__ qf_ws, const unsigned short* __restrict__ kt,
    const unsigned short* __restrict__ vt, const float* __restrict__ x,
    const float* __restrict__ gamma, float* __restrict__ out)
{
    // Double-buffered K+V tile (2 x 64 chunks x 1KB = 128KB), overlaid with
    // the O-reduction scratch (used only after the main loop + barrier).
    __shared__ __align__(16) union SMem {
        unsigned short t[2][64][64][8];   // [buf][chunk][lane][8 shorts]
        float red[64 * 132];              // 33.8KB, aliases buf 0
    } sm;
    __shared__ float l_s[8][32];

    const int bid = blockIdx.x;
    const int bb  = bid & 7;
    const int s   = bid >> 3;        // n-strip 0..63 (64 rows each)
    const int n0  = s * 64;
    const int tid = threadIdx.x;
    const int w    = tid >> 6;       // wave 0..7
    const int wq   = w & 3;          // m-quarter
    const int g    = w >> 2;         // n-group (0: rows 0-31, 1: rows 32-63)
    const int lane = tid & 63;
    const int quad = lane >> 4;
    const int l16  = lane & 15;

    // ---- Q fragments for this wave's 32-row n-strip: iteration-invariant
    v8bf qf[2][4];
    {
        const unsigned short* qb = qf_ws + ((size_t)(bb * 128 + s * 2 + g)) * 4096;
        #pragma unroll
        for (int ni = 0; ni < 2; ++ni)
            #pragma unroll
            for (int kc = 0; kc < 4; ++kc)
                qf[ni][kc] = *(const v8bf*)(qb + ((size_t)(ni * 4 + kc) * 64 + lane) * 8);
    }

    v4f oacc[8][2];  // [cb][ni] partial O over this wave's 32-m subset
    #pragma unroll
    for (int i = 0; i < 8; ++i)
        #pragma unroll
        for (int j = 0; j < 2; ++j)
            oacc[i][j] = (v4f){0.f, 0.f, 0.f, 0.f};
    float lpart[2] = {0.f, 0.f};
    const v4f Z4v = {0.f, 0.f, 0.f, 0.f};

    const int la = ((((quad & 1) << 1) << 4) + l16) << 2;  // bpermute byte idx
    const int lb = la + 64;

    // Stage source base: waves 0-3 pull K chunks, 4-7 pull V chunks.
    const unsigned short* ktb = kt + ((size_t)(bb * 32)) * 16384;
    const unsigned short* vtb = vt + ((size_t)(bb * 32)) * 16384;
    const unsigned short* stbase = ((w < 4) ? ktb : vtb)
                                 + (size_t)wq * 4096 + (size_t)lane * 8;

    v8bf kf[2][4], vv[8], pf[2];
    v4f sacc[2][2];

    STAGE(0, 0)
    asm volatile("s_waitcnt vmcnt(0)" ::: "memory");
    __syncthreads();

    for (int it = 0; it < 32; ++it) {
        const int cur = it & 1;
        STAGE((it + 1) & 31, cur ^ 1)   // prefetch next tile into other buffer
        LOADK(cur)
        LOADV(cur)
        SCOMP(sacc)                     // 16 S-MFMAs (ds_reads drain under them)
        SOFTMAX(sacc)                   // 16 exp2 + pack + bpermute
        PVOP                            // 16 PV-MFMAs
        asm volatile("s_waitcnt vmcnt(0)" ::: "memory");
        __syncthreads();                // next tile staged; this buf reusable
    }

    // ---- softmax denominators (per-wave partials over its 32-m subset)
    #pragma unroll
    for (int ni = 0; ni < 2; ++ni) {
        float r = lpart[ni];
        r += __shfl_xor(r, 16);
        r += __shfl_xor(r, 32);
        if (lane < 16) l_s[w][ni * 16 + lane] = r;
    }

    // All waves done with sm.t before red (aliased) is written.
    __syncthreads();

    // ---- O reduction across the 4 m-quarter waves (both n-groups concurrent)
    for (int rw = 0; rw < 4; ++rw) {
        if (wq == rw) {
            #pragma unroll
            for (int cb = 0; cb < 8; ++cb)
                #pragma unroll
                for (int ni = 0; ni < 2; ++ni) {
                    float* p = &sm.red[(g * 32 + ni * 16 + l16) * 132 + cb * 16 + quad * 4];
                    if (rw == 0) *(v4f*)p = oacc[cb][ni];
                    else {
                        v4f tv = *(const v4f*)p;
                        tv += oacc[cb][ni];
                        *(v4f*)p = tv;
                    }
                }
        }
        __syncthreads();
    }

    // ---- epilogue: out = gamma * O / l + x  (thread: n = tid&63, c-group = tid>>6)
    const float gm = gamma[0];
    const int   n  = tid & 63;
    const int  cg  = tid >> 6;       // 0..7
    const int  gr  = (n >> 5) * 4;   // l_s row base for this n's group
    const float li = 1.0f / (((l_s[gr + 0][n & 31] + l_s[gr + 1][n & 31])
                            + (l_s[gr + 2][n & 31] + l_s[gr + 3][n & 31])));
    #pragma unroll
    for (int j = 0; j < 16; ++j) {
        const int c = cg * 16 + j;
        const size_t idx = ((size_t)(bb * C_ + c)) * N_ + n0 + n;
        out[idx] = gm * sm.red[n * 132 + c] * li + x[idx];
    }
}

// ---------------------------------------------------------------------------
extern "C" void kernel_launch(void* const* d_in, const int* in_sizes, int n_in,
                              void* d_out, int out_size, void* d_ws, size_t ws_size,
                              hipStream_t stream)
{
    (void)in_sizes; (void)n_in; (void)out_size; (void)ws_size;
    const float* x     = (const float*)d_in[0];
    const float* dw_q  = (const float*)d_in[1];
    const float* pw_q  = (const float*)d_in[2];
    const float* dw_k  = (const float*)d_in[3];
    const float* pw_k  = (const float*)d_in[4];
    const float* dw_v  = (const float*)d_in[5];
    const float* pw_v  = (const float*)d_in[6];
    const float* gamma = (const float*)d_in[7];
    float* out = (float*)d_out;

    unsigned short* qf_ws = (unsigned short*)d_ws;                  // 8 MB
    unsigned short* kt    = qf_ws + (size_t)B_ * N_ * C_;           // 8 MB
    unsigned short* vt    = kt    + (size_t)B_ * N_ * C_;           // 8 MB

    proj_kernel<<<dim3(768), dim3(256), 0, stream>>>(
        x, dw_q, pw_q, dw_k, pw_k, dw_v, pw_v, qf_ws, kt, vt);
    attn_kernel<<<dim3(512), dim3(512), 0, stream>>>(
        qf_ws, kt, vt, x, gamma, out);
}

// Round 5
// 190.104 us; speedup vs baseline: 1.0570x; 1.0570x over previous
//
#include <hip/hip_runtime.h>
#include <hip/hip_bf16.h>

// PAM module R11: MEASUREMENT ROUND. R10 (K/V-through-LDS, 1 block/CU) regressed
// attn 97->118 and is reverted; attn returns to the R7 structure (best: 96.7-97.4).
// proj returns to R9 (swizzled tiles). The only change: proj is launched TWICE
// (idempotent -- writes identical bytes both times). Purpose: decompose dur_us.
//   P(proj) = total_R11 - 174.06 - ~2us(graph node)
// Static models say proj <= 20us but the R9 swizzle's -5us says otherwise; three
// rounds of attn grafts were null while ~77us of non-attn time sits unexplained.
// Decision tree: P >= 45 -> proj rewrite next (64-row strips / 4 blocks/CU +
// shared-x 3-in-1). P <= 20 -> rest is harness overhead; attn is the only lever.
//
// Workspace layouts (bf16, chunk = 64 lanes x 16B = 1KB, frag-major):
//   qf_ws[b][strip32][ni2][kc4][lane]         8MB  (PRE-SCALED by log2e)
//   kt   [b][tile128][mb8][kc4][lane]         8MB
//   vt   [b][tile128][cb*16+wq][l16]{8}       8MB

typedef __bf16 v8bf __attribute__((ext_vector_type(8)));
typedef float  v4f  __attribute__((ext_vector_type(4)));

#define B_ 8
#define C_ 128
#define N_ 4096

// Swizzled LDS offset (in shorts) for proj's 128x160 tiles (R9).
#define SWZ(R, COLS) ((R) * 160 + (((((COLS) >> 3) ^ (((R) >> 2) & 15))) << 3) + ((COLS) & 7))

static __device__ __forceinline__ unsigned short f2bf_rne(float f) {
    union { float f; unsigned u; } v; v.f = f;
    return (unsigned short)((v.u + 0x7fffu + ((v.u >> 16) & 1u)) >> 16);
}
static __device__ __forceinline__ unsigned fbits(float f) {
    union { float f; unsigned u; } v; v.f = f; return v.u;
}

// ---------------------------------------------------------------------------
// Kernel 1: q/k/v projections (R9 verbatim: swizzled 160-stride LDS tiles).
// ---------------------------------------------------------------------------
__global__ __launch_bounds__(256, 2) void proj_kernel(
    const float* __restrict__ x,
    const float* __restrict__ dw_q, const float* __restrict__ pw_q,
    const float* __restrict__ dw_k, const float* __restrict__ pw_k,
    const float* __restrict__ dw_v, const float* __restrict__ pw_v,
    unsigned short* __restrict__ qf_ws, unsigned short* __restrict__ kt,
    unsigned short* __restrict__ vt)
{
    __shared__ unsigned short xT[128 * 160];  // xT[n][c], swizzled
    __shared__ unsigned short Ws[128 * 160];  // W[o][c], swizzled; reused as store scratch

    const int bid = blockIdx.x;
    const int bb  = bid & 7;
    const int t   = (bid >> 3) & 31;
    const int pp  = bid >> 8;            // 0:q 1:k 2:v
    const int n0  = t * 128;
    const int tid = threadIdx.x;
    const int w    = tid >> 6;
    const int lane = tid & 63;
    const int quad = lane >> 4;
    const int l16  = lane & 15;

    #pragma unroll
    for (int k = 0; k < 16; ++k) {
        const int idx = tid + k * 256;
        const int c  = idx >> 5;
        const int nq = idx & 31;
        float4 f = *(const float4*)(x + ((size_t)(bb * C_ + c)) * N_ + n0 + nq * 4);
        xT[SWZ(nq * 4 + 0, c)] = f2bf_rne(f.x);
        xT[SWZ(nq * 4 + 1, c)] = f2bf_rne(f.y);
        xT[SWZ(nq * 4 + 2, c)] = f2bf_rne(f.z);
        xT[SWZ(nq * 4 + 3, c)] = f2bf_rne(f.w);
    }
    const float* pw = (pp == 0) ? pw_q : (pp == 1) ? pw_k : pw_v;
    const float* dw = (pp == 0) ? dw_q : (pp == 1) ? dw_k : dw_v;
    const float qs = (pp == 0) ? 1.4426950408889634f : 1.0f;
    #pragma unroll
    for (int k = 0; k < 16; ++k) {
        const int idx = tid + k * 256;
        const int o  = idx >> 5;
        const int c4 = (idx & 31) * 4;
        float4 p4 = *(const float4*)(pw + o * 128 + c4);
        float4 d4 = *(const float4*)(dw + c4);
        unsigned lo = (unsigned)f2bf_rne(p4.x * d4.x * qs) | ((unsigned)f2bf_rne(p4.y * d4.y * qs) << 16);
        unsigned hi = (unsigned)f2bf_rne(p4.z * d4.z * qs) | ((unsigned)f2bf_rne(p4.w * d4.w * qs) << 16);
        *(unsigned long long*)&Ws[SWZ(o, c4)] =
            (unsigned long long)lo | ((unsigned long long)hi << 32);
    }
    __syncthreads();

    const unsigned short* As = (pp < 2) ? xT : Ws;
    const unsigned short* Bs = (pp < 2) ? Ws : xT;

    v4f acc[2][8];
    #pragma unroll
    for (int i = 0; i < 2; ++i)
        #pragma unroll
        for (int j = 0; j < 8; ++j)
            acc[i][j] = (v4f){0.f, 0.f, 0.f, 0.f};

    #pragma unroll
    for (int kc = 0; kc < 4; ++kc) {
        v8bf av[2];
        #pragma unroll
        for (int i = 0; i < 2; ++i)
            av[i] = *(const v8bf*)&As[SWZ(w * 32 + i * 16 + l16, kc * 32 + quad * 8)];
        #pragma unroll
        for (int cb = 0; cb < 8; ++cb) {
            v8bf bv = *(const v8bf*)&Bs[SWZ(cb * 16 + l16, kc * 32 + quad * 8)];
            acc[0][cb] = __builtin_amdgcn_mfma_f32_16x16x32_bf16(av[0], bv, acc[0][cb], 0, 0, 0);
            acc[1][cb] = __builtin_amdgcn_mfma_f32_16x16x32_bf16(av[1], bv, acc[1][cb], 0, 0, 0);
        }
    }
    __syncthreads();

    unsigned short* sc = Ws;
    #pragma unroll
    for (int mi = 0; mi < 2; ++mi)
        #pragma unroll
        for (int cb = 0; cb < 8; ++cb)
            #pragma unroll
            for (int r = 0; r < 4; ++r)
                sc[SWZ(w * 32 + mi * 16 + quad * 4 + r, cb * 16 + l16)] =
                    f2bf_rne(acc[mi][cb][r]);
    __syncthreads();

    if (pp == 0) {
        unsigned short* dst = qf_ws + ((size_t)(bb * 64 + t * 2)) * 8192;
        #pragma unroll
        for (int p = 0; p < 8; ++p) {
            const int g     = p * 4 + w;
            const int strip = g >> 4, ni = (g >> 2) & 3, kc = g & 3;
            *(uint4*)(dst + ((size_t)g * 64 + lane) * 8) =
                *(const uint4*)&sc[SWZ(strip * 64 + ni * 16 + l16, kc * 32 + quad * 8)];
        }
    } else if (pp == 1) {
        unsigned short* dst = kt + ((size_t)(bb * 32 + t)) * 16384;
        #pragma unroll
        for (int p = 0; p < 8; ++p) {
            const int g  = p * 4 + w;
            const int mb = g >> 2, kc = g & 3;
            *(uint4*)(dst + ((size_t)g * 64 + lane) * 8) =
                *(const uint4*)&sc[SWZ(mb * 16 + l16, kc * 32 + quad * 8)];
        }
    } else {
        unsigned short* dst = vt + ((size_t)(bb * 32 + t)) * 16384;
        #pragma unroll
        for (int p = 0; p < 8; ++p) {
            const int d  = p * 256 + tid;
            const int cb = d >> 8, wq = (d >> 4) & 15, l = d & 15;
            *(uint4*)(dst + (size_t)d * 8) =
                *(const uint4*)&sc[SWZ(cb * 16 + l, wq * 8)];
        }
    }
}

// ---------------------------------------------------------------------------
// Kernel 2: attention (R7 structure verbatim -- best measured: 96.7-97.4us).
// grid 1024 = (b = bid&7, 32-row n-strip = bid>>3). 256 thr / 4 waves;
// wave = m-quarter, full c=128, n=32. Dual-sacc pipeline: softmax(t)
// interleaved with S-MFMAs of t+1; K register ping-pong; V single-buffer.
// ---------------------------------------------------------------------------
#define MFMA(A, B, C) __builtin_amdgcn_mfma_f32_16x16x32_bf16(A, B, C, 0, 0, 0)
#define EXP2(X) __builtin_amdgcn_exp2f(X)
#define PKPERM(EH, EL) __builtin_amdgcn_perm(fbits(EH), fbits(EL), 0x07060302)

#define LOADK(KF, TILE) { \
    const unsigned short* kp_ = kbase + (size_t)(TILE) * 16384; \
    _Pragma("unroll") \
    for (int mi_ = 0; mi_ < 2; ++mi_) \
        _Pragma("unroll") \
        for (int kc_ = 0; kc_ < 4; ++kc_) \
            KF[mi_][kc_] = *(const v8bf*)(kp_ + (size_t)((mi_ * 4 + kc_) * 64) * 8); \
}

#define LOADV(TILE) { \
    const unsigned short* vp_ = vbase + (size_t)(TILE) * 16384; \
    _Pragma("unroll") \
    for (int cb_ = 0; cb_ < 8; ++cb_) \
        vf[cb_] = *(const v8bf*)(vp_ + (size_t)(cb_ * 256) * 8); \
}

#define MKPF(NI, PK0A, PK0B, PK1A, PK1B) { \
    unsigned sLo_ = (quad < 2) ? PK0A : PK1A; \
    unsigned sHi_ = (quad < 2) ? PK0B : PK1B; \
    union { unsigned u[4]; v8bf v; } pu_; \
    pu_.u[0] = (unsigned)__builtin_amdgcn_ds_bpermute(la, (int)sLo_); \
    pu_.u[1] = (unsigned)__builtin_amdgcn_ds_bpermute(la, (int)sHi_); \
    pu_.u[2] = (unsigned)__builtin_amdgcn_ds_bpermute(lb, (int)sLo_); \
    pu_.u[3] = (unsigned)__builtin_amdgcn_ds_bpermute(lb, (int)sHi_); \
    pf[NI] = pu_.v; \
}

#define SCOMP0(KF, SC) { \
    _Pragma("unroll") \
    for (int mi_ = 0; mi_ < 2; ++mi_) \
        _Pragma("unroll") \
        for (int ni_ = 0; ni_ < 2; ++ni_) { \
            v4f a_ = MFMA(KF[mi_][0], qf[ni_][0], Z4v); \
            _Pragma("unroll") \
            for (int kc_ = 1; kc_ < 4; ++kc_) \
                a_ = MFMA(KF[mi_][kc_], qf[ni_][kc_], a_); \
            SC[mi_][ni_] = a_; \
        } \
}

// softmax(SC_IN) hand-interleaved with the 16 S-MFMAs of the next tile.
#define FUSED(SC_IN, KF, SC_OUT) { \
    float e0_, e1_, e2_, e3_; \
    unsigned pk00a_, pk00b_, pk10a_, pk10b_, pk01a_, pk01b_, pk11a_, pk11b_; \
    SC_OUT[0][0] = MFMA(KF[0][0], qf[0][0], Z4v); \
    SC_OUT[0][1] = MFMA(KF[0][0], qf[1][0], Z4v); \
    e0_ = EXP2(SC_IN[0][0][0]); e1_ = EXP2(SC_IN[0][0][1]); \
    e2_ = EXP2(SC_IN[0][0][2]); e3_ = EXP2(SC_IN[0][0][3]); \
    SC_OUT[0][0] = MFMA(KF[0][1], qf[0][1], SC_OUT[0][0]); \
    SC_OUT[0][1] = MFMA(KF[0][1], qf[1][1], SC_OUT[0][1]); \
    lpart[0] += (e0_ + e1_) + (e2_ + e3_); \
    pk00a_ = PKPERM(e1_, e0_); pk00b_ = PKPERM(e3_, e2_); \
    SC_OUT[0][0] = MFMA(KF[0][2], qf[0][2], SC_OUT[0][0]); \
    SC_OUT[0][1] = MFMA(KF[0][2], qf[1][2], SC_OUT[0][1]); \
    e0_ = EXP2(SC_IN[1][0][0]); e1_ = EXP2(SC_IN[1][0][1]); \
    e2_ = EXP2(SC_IN[1][0][2]); e3_ = EXP2(SC_IN[1][0][3]); \
    SC_OUT[0][0] = MFMA(KF[0][3], qf[0][3], SC_OUT[0][0]); \
    SC_OUT[0][1] = MFMA(KF[0][3], qf[1][3], SC_OUT[0][1]); \
    lpart[0] += (e0_ + e1_) + (e2_ + e3_); \
    pk10a_ = PKPERM(e1_, e0_); pk10b_ = PKPERM(e3_, e2_); \
    SC_OUT[1][0] = MFMA(KF[1][0], qf[0][0], Z4v); \
    SC_OUT[1][1] = MFMA(KF[1][0], qf[1][0], Z4v); \
    MKPF(0, pk00a_, pk00b_, pk10a_, pk10b_) \
    SC_OUT[1][0] = MFMA(KF[1][1], qf[0][1], SC_OUT[1][0]); \
    SC_OUT[1][1] = MFMA(KF[1][1], qf[1][1], SC_OUT[1][1]); \
    e0_ = EXP2(SC_IN[0][1][0]); e1_ = EXP2(SC_IN[0][1][1]); \
    e2_ = EXP2(SC_IN[0][1][2]); e3_ = EXP2(SC_IN[0][1][3]); \
    SC_OUT[1][0] = MFMA(KF[1][2], qf[0][2], SC_OUT[1][0]); \
    SC_OUT[1][1] = MFMA(KF[1][2], qf[1][2], SC_OUT[1][1]); \
    lpart[1] += (e0_ + e1_) + (e2_ + e3_); \
    pk01a_ = PKPERM(e1_, e0_); pk01b_ = PKPERM(e3_, e2_); \
    SC_OUT[1][0] = MFMA(KF[1][3], qf[0][3], SC_OUT[1][0]); \
    SC_OUT[1][1] = MFMA(KF[1][3], qf[1][3], SC_OUT[1][1]); \
    e0_ = EXP2(SC_IN[1][1][0]); e1_ = EXP2(SC_IN[1][1][1]); \
    e2_ = EXP2(SC_IN[1][1][2]); e3_ = EXP2(SC_IN[1][1][3]); \
    lpart[1] += (e0_ + e1_) + (e2_ + e3_); \
    pk11a_ = PKPERM(e1_, e0_); pk11b_ = PKPERM(e3_, e2_); \
    MKPF(1, pk01a_, pk01b_, pk11a_, pk11b_) \
}

#define PVOP { \
    _Pragma("unroll") \
    for (int ni_ = 0; ni_ < 2; ++ni_) \
        _Pragma("unroll") \
        for (int cb_ = 0; cb_ < 8; ++cb_) \
            oacc[cb_][ni_] = MFMA(vf[cb_], pf[ni_], oacc[cb_][ni_]); \
}

__global__ __launch_bounds__(256, 2) void attn_kernel(
    const unsigned short* __restrict__ qf_ws, const unsigned short* __restrict__ kt,
    const unsigned short* __restrict__ vt, const float* __restrict__ x,
    const float* __restrict__ gamma, float* __restrict__ out)
{
    __shared__ float red[32 * 132];   // O reduction scratch [n][c] (+pad)
    __shared__ float l_s[4][32];

    const int bid = blockIdx.x;
    const int bb  = bid & 7;
    const int s   = bid >> 3;        // n-strip 0..127 (32 rows each)
    const int n0  = s * 32;
    const int tid = threadIdx.x;
    const int w    = tid >> 6;       // wave = m-quarter owner
    const int lane = tid & 63;
    const int quad = lane >> 4;
    const int l16  = lane & 15;

    // ---- Q fragments (n=32 strip): 32 VGPR, iteration-invariant
    v8bf qf[2][4];
    {
        const unsigned short* qb = qf_ws + ((size_t)(bb * 128 + s)) * 4096;
        #pragma unroll
        for (int ni = 0; ni < 2; ++ni)
            #pragma unroll
            for (int kc = 0; kc < 4; ++kc)
                qf[ni][kc] = *(const v8bf*)(qb + ((size_t)(ni * 4 + kc) * 64 + lane) * 8);
    }

    v4f oacc[8][2];  // 64 regs: [cb][ni] partial O over this wave's 32-m subset
    #pragma unroll
    for (int i = 0; i < 8; ++i)
        #pragma unroll
        for (int j = 0; j < 2; ++j)
            oacc[i][j] = (v4f){0.f, 0.f, 0.f, 0.f};
    float lpart[2] = {0.f, 0.f};
    const v4f Z4v = {0.f, 0.f, 0.f, 0.f};

    const int la = ((((quad & 1) << 1) << 4) + l16) << 2;  // bpermute byte idx
    const int lb = la + 64;

    const unsigned short* kbase = kt + ((size_t)(bb * 32)) * 16384 + ((size_t)(w * 8) * 64 + lane) * 8;
    const unsigned short* vbase = vt + ((size_t)(bb * 32)) * 16384 + ((size_t)(w * 64 + lane)) * 8;

    v8bf kfA[2][4], kfB[2][4], vf[8];
    v4f sc0[2][2], sc1[2][2];
    v8bf pf[2];

    LOADK(kfA, 0)
    LOADV(0)
    LOADK(kfB, 1)
    SCOMP0(kfA, sc0)                 // S(0)

    for (int it = 0; it < 32; it += 2) {
        LOADK(kfA, (it + 2) & 31)    // K(t+2) in flight across this half-step
        FUSED(sc0, kfB, sc1)         // softmax(t) || S(t+1)
        PVOP                          // PV(t), consumes vf = V(t)
        LOADV((it + 1) & 31)
        LOADK(kfB, (it + 3) & 31)
        FUSED(sc1, kfA, sc0)         // softmax(t+1) || S(t+2)
        PVOP                          // PV(t+1)
        LOADV((it + 2) & 31)
    }

    // ---- softmax denominators (per-wave partials over its 32-m subset)
    #pragma unroll
    for (int ni = 0; ni < 2; ++ni) {
        float r = lpart[ni];
        r += __shfl_xor(r, 16);
        r += __shfl_xor(r, 32);
        if (lane < 16) l_s[w][ni * 16 + lane] = r;
    }

    // ---- O reduction across the 4 m-quarter waves
    for (int rw = 0; rw < 4; ++rw) {
        if (w == rw) {
            #pragma unroll
            for (int cb = 0; cb < 8; ++cb)
                #pragma unroll
                for (int ni = 0; ni < 2; ++ni) {
                    float* p = &red[(ni * 16 + l16) * 132 + cb * 16 + quad * 4];
                    if (rw == 0) *(v4f*)p = oacc[cb][ni];
                    else {
                        v4f tv = *(const v4f*)p;
                        tv += oacc[cb][ni];
                        *(v4f*)p = tv;
                    }
                }
        }
        __syncthreads();
    }

    // ---- epilogue: out = gamma * O / l + x  (thread: n = tid&31, c-group = tid>>5)
    const float g = gamma[0];
    const int   n = tid & 31;
    const int  cg = tid >> 5;        // 0..7
    const float li = 1.0f / (((l_s[0][n] + l_s[1][n]) + (l_s[2][n] + l_s[3][n])));
    #pragma unroll
    for (int j = 0; j < 16; ++j) {
        const int c = cg * 16 + j;
        const size_t idx = ((size_t)(bb * C_ + c)) * N_ + n0 + n;
        out[idx] = g * red[n * 132 + c] * li + x[idx];
    }
}

// ---------------------------------------------------------------------------
extern "C" void kernel_launch(void* const* d_in, const int* in_sizes, int n_in,
                              void* d_out, int out_size, void* d_ws, size_t ws_size,
                              hipStream_t stream)
{
    (void)in_sizes; (void)n_in; (void)out_size; (void)ws_size;
    const float* x     = (const float*)d_in[0];
    const float* dw_q  = (const float*)d_in[1];
    const float* pw_q  = (const float*)d_in[2];
    const float* dw_k  = (const float*)d_in[3];
    const float* pw_k  = (const float*)d_in[4];
    const float* dw_v  = (const float*)d_in[5];
    const float* pw_v  = (const float*)d_in[6];
    const float* gamma = (const float*)d_in[7];
    float* out = (float*)d_out;

    unsigned short* qf_ws = (unsigned short*)d_ws;                  // 8 MB
    unsigned short* kt    = qf_ws + (size_t)B_ * N_ * C_;           // 8 MB
    unsigned short* vt    = kt    + (size_t)B_ * N_ * C_;           // 8 MB

    // MEASUREMENT: proj launched twice (idempotent). The extra time over the
    // 174.06us R9 baseline IS proj's true cost (minus ~2us graph-node overhead).
    proj_kernel<<<dim3(768), dim3(256), 0, stream>>>(
        x, dw_q, pw_q, dw_k, pw_k, dw_v, pw_v, qf_ws, kt, vt);
    proj_kernel<<<dim3(768), dim3(256), 0, stream>>>(
        x, dw_q, pw_q, dw_k, pw_k, dw_v, pw_v, qf_ws, kt, vt);
    attn_kernel<<<dim3(1024), dim3(256), 0, stream>>>(
        qf_ws, kt, vt, x, gamma, out);
}

// Round 6
// 187.358 us; speedup vs baseline: 1.0725x; 1.0147x over previous
//
#include <hip/hip_runtime.h>
#include <hip/hip_bf16.h>

// PAM module R12: q/k/v 1x1 projections -> bf16 MFMA attention -> gamma*out + x.
// R11 measurement: proj ~15us, attn ~97us, fixed harness residue ~60us. attn is
// the only lever. Theory: attn is L3-bandwidth-bound (2GB K/V reads / 97us =
// 20.6 TB/s; per-batch working set 8MB > 4MB per-XCD L2). R12 halves traffic
// WITHOUT changing the proven R7 execution model: 512-thread blocks, 8 waves =
// 4 m-quarters x 2 n-groups; per-wave code is R7 VERBATIM (register K ping-pong,
// dual-sacc FUSED pipeline, register V). The g-paired waves share identical
// kbase/vbase -> identical loads; a raw s_barrier (no waitcnt) per half-step
// keeps them temporally aligned so the second reader hits L1/L2 instead of L3.
// Epilogue = R10's 8-wave reduction (harness-passed). Grid 512.
//
// Workspace layouts (bf16, chunk = 64 lanes x 16B = 1KB, frag-major):
//   qf_ws[b][strip32][ni2][kc4][lane]         8MB  (PRE-SCALED by log2e)
//   kt   [b][tile128][mb8][kc4][lane]         8MB
//   vt   [b][tile128][cb*16+wq][l16]{8}       8MB

typedef __bf16 v8bf __attribute__((ext_vector_type(8)));
typedef float  v4f  __attribute__((ext_vector_type(4)));

#define B_ 8
#define C_ 128
#define N_ 4096

// Swizzled LDS offset (in shorts) for proj's 128x160 tiles (R9).
#define SWZ(R, COLS) ((R) * 160 + (((((COLS) >> 3) ^ (((R) >> 2) & 15))) << 3) + ((COLS) & 7))

static __device__ __forceinline__ unsigned short f2bf_rne(float f) {
    union { float f; unsigned u; } v; v.f = f;
    return (unsigned short)((v.u + 0x7fffu + ((v.u >> 16) & 1u)) >> 16);
}
static __device__ __forceinline__ unsigned fbits(float f) {
    union { float f; unsigned u; } v; v.f = f; return v.u;
}

// ---------------------------------------------------------------------------
// Kernel 1: q/k/v projections (R9 verbatim: swizzled 160-stride LDS tiles).
// ---------------------------------------------------------------------------
__global__ __launch_bounds__(256, 2) void proj_kernel(
    const float* __restrict__ x,
    const float* __restrict__ dw_q, const float* __restrict__ pw_q,
    const float* __restrict__ dw_k, const float* __restrict__ pw_k,
    const float* __restrict__ dw_v, const float* __restrict__ pw_v,
    unsigned short* __restrict__ qf_ws, unsigned short* __restrict__ kt,
    unsigned short* __restrict__ vt)
{
    __shared__ unsigned short xT[128 * 160];  // xT[n][c], swizzled
    __shared__ unsigned short Ws[128 * 160];  // W[o][c], swizzled; reused as store scratch

    const int bid = blockIdx.x;
    const int bb  = bid & 7;
    const int t   = (bid >> 3) & 31;
    const int pp  = bid >> 8;            // 0:q 1:k 2:v
    const int n0  = t * 128;
    const int tid = threadIdx.x;
    const int w    = tid >> 6;
    const int lane = tid & 63;
    const int quad = lane >> 4;
    const int l16  = lane & 15;

    #pragma unroll
    for (int k = 0; k < 16; ++k) {
        const int idx = tid + k * 256;
        const int c  = idx >> 5;
        const int nq = idx & 31;
        float4 f = *(const float4*)(x + ((size_t)(bb * C_ + c)) * N_ + n0 + nq * 4);
        xT[SWZ(nq * 4 + 0, c)] = f2bf_rne(f.x);
        xT[SWZ(nq * 4 + 1, c)] = f2bf_rne(f.y);
        xT[SWZ(nq * 4 + 2, c)] = f2bf_rne(f.z);
        xT[SWZ(nq * 4 + 3, c)] = f2bf_rne(f.w);
    }
    const float* pw = (pp == 0) ? pw_q : (pp == 1) ? pw_k : pw_v;
    const float* dw = (pp == 0) ? dw_q : (pp == 1) ? dw_k : dw_v;
    const float qs = (pp == 0) ? 1.4426950408889634f : 1.0f;
    #pragma unroll
    for (int k = 0; k < 16; ++k) {
        const int idx = tid + k * 256;
        const int o  = idx >> 5;
        const int c4 = (idx & 31) * 4;
        float4 p4 = *(const float4*)(pw + o * 128 + c4);
        float4 d4 = *(const float4*)(dw + c4);
        unsigned lo = (unsigned)f2bf_rne(p4.x * d4.x * qs) | ((unsigned)f2bf_rne(p4.y * d4.y * qs) << 16);
        unsigned hi = (unsigned)f2bf_rne(p4.z * d4.z * qs) | ((unsigned)f2bf_rne(p4.w * d4.w * qs) << 16);
        *(unsigned long long*)&Ws[SWZ(o, c4)] =
            (unsigned long long)lo | ((unsigned long long)hi << 32);
    }
    __syncthreads();

    const unsigned short* As = (pp < 2) ? xT : Ws;
    const unsigned short* Bs = (pp < 2) ? Ws : xT;

    v4f acc[2][8];
    #pragma unroll
    for (int i = 0; i < 2; ++i)
        #pragma unroll
        for (int j = 0; j < 8; ++j)
            acc[i][j] = (v4f){0.f, 0.f, 0.f, 0.f};

    #pragma unroll
    for (int kc = 0; kc < 4; ++kc) {
        v8bf av[2];
        #pragma unroll
        for (int i = 0; i < 2; ++i)
            av[i] = *(const v8bf*)&As[SWZ(w * 32 + i * 16 + l16, kc * 32 + quad * 8)];
        #pragma unroll
        for (int cb = 0; cb < 8; ++cb) {
            v8bf bv = *(const v8bf*)&Bs[SWZ(cb * 16 + l16, kc * 32 + quad * 8)];
            acc[0][cb] = __builtin_amdgcn_mfma_f32_16x16x32_bf16(av[0], bv, acc[0][cb], 0, 0, 0);
            acc[1][cb] = __builtin_amdgcn_mfma_f32_16x16x32_bf16(av[1], bv, acc[1][cb], 0, 0, 0);
        }
    }
    __syncthreads();

    unsigned short* sc = Ws;
    #pragma unroll
    for (int mi = 0; mi < 2; ++mi)
        #pragma unroll
        for (int cb = 0; cb < 8; ++cb)
            #pragma unroll
            for (int r = 0; r < 4; ++r)
                sc[SWZ(w * 32 + mi * 16 + quad * 4 + r, cb * 16 + l16)] =
                    f2bf_rne(acc[mi][cb][r]);
    __syncthreads();

    if (pp == 0) {
        unsigned short* dst = qf_ws + ((size_t)(bb * 64 + t * 2)) * 8192;
        #pragma unroll
        for (int p = 0; p < 8; ++p) {
            const int g     = p * 4 + w;
            const int strip = g >> 4, ni = (g >> 2) & 3, kc = g & 3;
            *(uint4*)(dst + ((size_t)g * 64 + lane) * 8) =
                *(const uint4*)&sc[SWZ(strip * 64 + ni * 16 + l16, kc * 32 + quad * 8)];
        }
    } else if (pp == 1) {
        unsigned short* dst = kt + ((size_t)(bb * 32 + t)) * 16384;
        #pragma unroll
        for (int p = 0; p < 8; ++p) {
            const int g  = p * 4 + w;
            const int mb = g >> 2, kc = g & 3;
            *(uint4*)(dst + ((size_t)g * 64 + lane) * 8) =
                *(const uint4*)&sc[SWZ(mb * 16 + l16, kc * 32 + quad * 8)];
        }
    } else {
        unsigned short* dst = vt + ((size_t)(bb * 32 + t)) * 16384;
        #pragma unroll
        for (int p = 0; p < 8; ++p) {
            const int d  = p * 256 + tid;
            const int cb = d >> 8, wq = (d >> 4) & 15, l = d & 15;
            *(uint4*)(dst + (size_t)d * 8) =
                *(const uint4*)&sc[SWZ(cb * 16 + l, wq * 8)];
        }
    }
}

// ---------------------------------------------------------------------------
// Kernel 2: attention. grid 512 = (b = bid&7, 64-row n-strip = bid>>3).
// 512 thr / 8 waves: wq = w&3 (m-quarter), g = w>>2 (n-group of 32 rows).
// Per-wave main loop is R7 verbatim; g-paired waves issue identical K/V loads
// and are kept aligned by a raw s_barrier per half-step (L1/L2 dedup).
// ---------------------------------------------------------------------------
#define MFMA(A, B, C) __builtin_amdgcn_mfma_f32_16x16x32_bf16(A, B, C, 0, 0, 0)
#define EXP2(X) __builtin_amdgcn_exp2f(X)
#define PKPERM(EH, EL) __builtin_amdgcn_perm(fbits(EH), fbits(EL), 0x07060302)

#define LOADK(KF, TILE) { \
    const unsigned short* kp_ = kbase + (size_t)(TILE) * 16384; \
    _Pragma("unroll") \
    for (int mi_ = 0; mi_ < 2; ++mi_) \
        _Pragma("unroll") \
        for (int kc_ = 0; kc_ < 4; ++kc_) \
            KF[mi_][kc_] = *(const v8bf*)(kp_ + (size_t)((mi_ * 4 + kc_) * 64) * 8); \
}

#define LOADV(TILE) { \
    const unsigned short* vp_ = vbase + (size_t)(TILE) * 16384; \
    _Pragma("unroll") \
    for (int cb_ = 0; cb_ < 8; ++cb_) \
        vf[cb_] = *(const v8bf*)(vp_ + (size_t)(cb_ * 256) * 8); \
}

#define MKPF(NI, PK0A, PK0B, PK1A, PK1B) { \
    unsigned sLo_ = (quad < 2) ? PK0A : PK1A; \
    unsigned sHi_ = (quad < 2) ? PK0B : PK1B; \
    union { unsigned u[4]; v8bf v; } pu_; \
    pu_.u[0] = (unsigned)__builtin_amdgcn_ds_bpermute(la, (int)sLo_); \
    pu_.u[1] = (unsigned)__builtin_amdgcn_ds_bpermute(la, (int)sHi_); \
    pu_.u[2] = (unsigned)__builtin_amdgcn_ds_bpermute(lb, (int)sLo_); \
    pu_.u[3] = (unsigned)__builtin_amdgcn_ds_bpermute(lb, (int)sHi_); \
    pf[NI] = pu_.v; \
}

#define SCOMP0(KF, SC) { \
    _Pragma("unroll") \
    for (int mi_ = 0; mi_ < 2; ++mi_) \
        _Pragma("unroll") \
        for (int ni_ = 0; ni_ < 2; ++ni_) { \
            v4f a_ = MFMA(KF[mi_][0], qf[ni_][0], Z4v); \
            _Pragma("unroll") \
            for (int kc_ = 1; kc_ < 4; ++kc_) \
                a_ = MFMA(KF[mi_][kc_], qf[ni_][kc_], a_); \
            SC[mi_][ni_] = a_; \
        } \
}

// softmax(SC_IN) hand-interleaved with the 16 S-MFMAs of the next tile.
#define FUSED(SC_IN, KF, SC_OUT) { \
    float e0_, e1_, e2_, e3_; \
    unsigned pk00a_, pk00b_, pk10a_, pk10b_, pk01a_, pk01b_, pk11a_, pk11b_; \
    SC_OUT[0][0] = MFMA(KF[0][0], qf[0][0], Z4v); \
    SC_OUT[0][1] = MFMA(KF[0][0], qf[1][0], Z4v); \
    e0_ = EXP2(SC_IN[0][0][0]); e1_ = EXP2(SC_IN[0][0][1]); \
    e2_ = EXP2(SC_IN[0][0][2]); e3_ = EXP2(SC_IN[0][0][3]); \
    SC_OUT[0][0] = MFMA(KF[0][1], qf[0][1], SC_OUT[0][0]); \
    SC_OUT[0][1] = MFMA(KF[0][1], qf[1][1], SC_OUT[0][1]); \
    lpart[0] += (e0_ + e1_) + (e2_ + e3_); \
    pk00a_ = PKPERM(e1_, e0_); pk00b_ = PKPERM(e3_, e2_); \
    SC_OUT[0][0] = MFMA(KF[0][2], qf[0][2], SC_OUT[0][0]); \
    SC_OUT[0][1] = MFMA(KF[0][2], qf[1][2], SC_OUT[0][1]); \
    e0_ = EXP2(SC_IN[1][0][0]); e1_ = EXP2(SC_IN[1][0][1]); \
    e2_ = EXP2(SC_IN[1][0][2]); e3_ = EXP2(SC_IN[1][0][3]); \
    SC_OUT[0][0] = MFMA(KF[0][3], qf[0][3], SC_OUT[0][0]); \
    SC_OUT[0][1] = MFMA(KF[0][3], qf[1][3], SC_OUT[0][1]); \
    lpart[0] += (e0_ + e1_) + (e2_ + e3_); \
    pk10a_ = PKPERM(e1_, e0_); pk10b_ = PKPERM(e3_, e2_); \
    SC_OUT[1][0] = MFMA(KF[1][0], qf[0][0], Z4v); \
    SC_OUT[1][1] = MFMA(KF[1][0], qf[1][0], Z4v); \
    MKPF(0, pk00a_, pk00b_, pk10a_, pk10b_) \
    SC_OUT[1][0] = MFMA(KF[1][1], qf[0][1], SC_OUT[1][0]); \
    SC_OUT[1][1] = MFMA(KF[1][1], qf[1][1], SC_OUT[1][1]); \
    e0_ = EXP2(SC_IN[0][1][0]); e1_ = EXP2(SC_IN[0][1][1]); \
    e2_ = EXP2(SC_IN[0][1][2]); e3_ = EXP2(SC_IN[0][1][3]); \
    SC_OUT[1][0] = MFMA(KF[1][2], qf[0][2], SC_OUT[1][0]); \
    SC_OUT[1][1] = MFMA(KF[1][2], qf[1][2], SC_OUT[1][1]); \
    lpart[1] += (e0_ + e1_) + (e2_ + e3_); \
    pk01a_ = PKPERM(e1_, e0_); pk01b_ = PKPERM(e3_, e2_); \
    SC_OUT[1][0] = MFMA(KF[1][3], qf[0][3], SC_OUT[1][0]); \
    SC_OUT[1][1] = MFMA(KF[1][3], qf[1][3], SC_OUT[1][1]); \
    e0_ = EXP2(SC_IN[1][1][0]); e1_ = EXP2(SC_IN[1][1][1]); \
    e2_ = EXP2(SC_IN[1][1][2]); e3_ = EXP2(SC_IN[1][1][3]); \
    lpart[1] += (e0_ + e1_) + (e2_ + e3_); \
    pk11a_ = PKPERM(e1_, e0_); pk11b_ = PKPERM(e3_, e2_); \
    MKPF(1, pk01a_, pk01b_, pk11a_, pk11b_) \
}

#define PVOP { \
    _Pragma("unroll") \
    for (int ni_ = 0; ni_ < 2; ++ni_) \
        _Pragma("unroll") \
        for (int cb_ = 0; cb_ < 8; ++cb_) \
            oacc[cb_][ni_] = MFMA(vf[cb_], pf[ni_], oacc[cb_][ni_]); \
}

__global__ __launch_bounds__(512, 2) void attn_kernel(
    const unsigned short* __restrict__ qf_ws, const unsigned short* __restrict__ kt,
    const unsigned short* __restrict__ vt, const float* __restrict__ x,
    const float* __restrict__ gamma, float* __restrict__ out)
{
    __shared__ float red[64 * 132];   // O reduction scratch [n][c] (+pad)
    __shared__ float l_s[8][32];

    const int bid = blockIdx.x;
    const int bb  = bid & 7;
    const int s   = bid >> 3;        // n-strip 0..63 (64 rows each)
    const int n0  = s * 64;
    const int tid = threadIdx.x;
    const int w    = tid >> 6;       // wave 0..7
    const int wq   = w & 3;          // m-quarter
    const int g    = w >> 2;         // n-group (0: rows 0-31, 1: rows 32-63)
    const int lane = tid & 63;
    const int quad = lane >> 4;
    const int l16  = lane & 15;

    // ---- Q fragments for this wave's 32-row n-strip: iteration-invariant
    v8bf qf[2][4];
    {
        const unsigned short* qb = qf_ws + ((size_t)(bb * 128 + s * 2 + g)) * 4096;
        #pragma unroll
        for (int ni = 0; ni < 2; ++ni)
            #pragma unroll
            for (int kc = 0; kc < 4; ++kc)
                qf[ni][kc] = *(const v8bf*)(qb + ((size_t)(ni * 4 + kc) * 64 + lane) * 8);
    }

    v4f oacc[8][2];  // [cb][ni] partial O over this wave's 32-m subset
    #pragma unroll
    for (int i = 0; i < 8; ++i)
        #pragma unroll
        for (int j = 0; j < 2; ++j)
            oacc[i][j] = (v4f){0.f, 0.f, 0.f, 0.f};
    float lpart[2] = {0.f, 0.f};
    const v4f Z4v = {0.f, 0.f, 0.f, 0.f};

    const int la = ((((quad & 1) << 1) << 4) + l16) << 2;  // bpermute byte idx
    const int lb = la + 64;

    // NOTE: no g dependence -> the two g-paired waves read IDENTICAL addresses.
    const unsigned short* kbase = kt + ((size_t)(bb * 32)) * 16384 + ((size_t)(wq * 8) * 64 + lane) * 8;
    const unsigned short* vbase = vt + ((size_t)(bb * 32)) * 16384 + ((size_t)(wq * 64 + lane)) * 8;

    v8bf kfA[2][4], kfB[2][4], vf[8];
    v4f sc0[2][2], sc1[2][2];
    v8bf pf[2];

    LOADK(kfA, 0)
    LOADV(0)
    LOADK(kfB, 1)
    SCOMP0(kfA, sc0)                 // S(0)

    for (int it = 0; it < 32; it += 2) {
        LOADK(kfA, (it + 2) & 31)    // K(t+2) in flight across this half-step
        FUSED(sc0, kfB, sc1)         // softmax(t) || S(t+1)
        PVOP                          // PV(t), consumes vf = V(t)
        LOADV((it + 1) & 31)
        __builtin_amdgcn_s_barrier();   // raw rendezvous: keep g-pairs aligned
        LOADK(kfB, (it + 3) & 31)
        FUSED(sc1, kfA, sc0)         // softmax(t+1) || S(t+2)
        PVOP                          // PV(t+1)
        LOADV((it + 2) & 31)
        __builtin_amdgcn_s_barrier();
    }

    // ---- softmax denominators (per-wave partials over its 32-m subset)
    #pragma unroll
    for (int ni = 0; ni < 2; ++ni) {
        float r = lpart[ni];
        r += __shfl_xor(r, 16);
        r += __shfl_xor(r, 32);
        if (lane < 16) l_s[w][ni * 16 + lane] = r;
    }

    __syncthreads();

    // ---- O reduction across the 4 m-quarter waves (both n-groups concurrent)
    for (int rw = 0; rw < 4; ++rw) {
        if (wq == rw) {
            #pragma unroll
            for (int cb = 0; cb < 8; ++cb)
                #pragma unroll
                for (int ni = 0; ni < 2; ++ni) {
                    float* p = &red[(g * 32 + ni * 16 + l16) * 132 + cb * 16 + quad * 4];
                    if (rw == 0) *(v4f*)p = oacc[cb][ni];
                    else {
                        v4f tv = *(const v4f*)p;
                        tv += oacc[cb][ni];
                        *(v4f*)p = tv;
                    }
                }
        }
        __syncthreads();
    }

    // ---- epilogue: out = gamma * O / l + x  (thread: n = tid&63, c-group = tid>>6)
    const float gm = gamma[0];
    const int   n  = tid & 63;
    const int  cg  = tid >> 6;       // 0..7
    const int  gr  = (n >> 5) * 4;   // l_s row base for this n's group
    const float li = 1.0f / (((l_s[gr + 0][n & 31] + l_s[gr + 1][n & 31])
                            + (l_s[gr + 2][n & 31] + l_s[gr + 3][n & 31])));
    #pragma unroll
    for (int j = 0; j < 16; ++j) {
        const int c = cg * 16 + j;
        const size_t idx = ((size_t)(bb * C_ + c)) * N_ + n0 + n;
        out[idx] = gm * red[n * 132 + c] * li + x[idx];
    }
}

// ---------------------------------------------------------------------------
extern "C" void kernel_launch(void* const* d_in, const int* in_sizes, int n_in,
                              void* d_out, int out_size, void* d_ws, size_t ws_size,
                              hipStream_t stream)
{
    (void)in_sizes; (void)n_in; (void)out_size; (void)ws_size;
    const float* x     = (const float*)d_in[0];
    const float* dw_q  = (const float*)d_in[1];
    const float* pw_q  = (const float*)d_in[2];
    const float* dw_k  = (const float*)d_in[3];
    const float* pw_k  = (const float*)d_in[4];
    const float* dw_v  = (const float*)d_in[5];
    const float* pw_v  = (const float*)d_in[6];
    const float* gamma = (const float*)d_in[7];
    float* out = (float*)d_out;

    unsigned short* qf_ws = (unsigned short*)d_ws;                  // 8 MB
    unsigned short* kt    = qf_ws + (size_t)B_ * N_ * C_;           // 8 MB
    unsigned short* vt    = kt    + (size_t)B_ * N_ * C_;           // 8 MB

    proj_kernel<<<dim3(768), dim3(256), 0, stream>>>(
        x, dw_q, pw_q, dw_k, pw_k, dw_v, pw_v, qf_ws, kt, vt);
    attn_kernel<<<dim3(512), dim3(512), 0, stream>>>(
        qf_ws, kt, vt, x, gamma, out);
}